// Round 12
// baseline (192.820 us; speedup 1.0000x reference)
//
#include <hip/hip_runtime.h>
#include <cmath>

#define B_ 2
#define T_ 2048
#define D_ 1024
#define H_ 16
#define HD_ 64
#define M_ (B_ * T_)   // 4096
#define N3_ (3 * D_)   // 3072
#define K_ 1024

typedef _Float16 halfx8 __attribute__((ext_vector_type(8)));
typedef _Float16 halfx4 __attribute__((ext_vector_type(4)));
typedef _Float16 halfx2 __attribute__((ext_vector_type(2)));
typedef __fp16 fp16x2 __attribute__((ext_vector_type(2)));
typedef float f32x4 __attribute__((ext_vector_type(4)));
typedef float f32x16 __attribute__((ext_vector_type(16)));

#define ASYNC_COPY16(gp, lp) \
  __builtin_amdgcn_global_load_lds((__attribute__((address_space(1))) void*)(gp), \
      (__attribute__((address_space(3))) void*)(lp), 16, 0, 0)

// q pre-scale: 1/sqrt(64) * log2(e)  (softmax in exp2 domain)
#define QSCALE 0.1803368801111204f
// defer-max rescale threshold (exp2 domain): P <= 2^4, fp16-safe partials
#define RTHR 4.0f

__device__ __forceinline__ float exp2fast(float x) {
#if __has_builtin(__builtin_amdgcn_exp2f)
    return __builtin_amdgcn_exp2f(x);
#else
    return exp2f(x);
#endif
}

// Hybrid decomposition: qt>=8 split into 2 chunks (chunk0 = kt 0..qt, all
// interior; chunk1 = kt qt+1..2qt+1, has the causal tail). qt<8 unsplit.
// 24 items per (b,h), ordered LPT-descending by visit count.
__device__ const int QT2_OF[24] = {15,15,7, 14,14, 13,13,6, 12,12, 11,11,5, 10,10, 9,9,4, 8,8, 3,2,1,0};
__device__ const int C2_OF[24]  = { 0, 1,0,  0, 1,  0, 1,0,  0, 1,  0, 1,0,  0, 1, 0,1,0,  0,1, 0,0,0,0};

// ---------------------------------------------------------------------------
// fused prep: fp32->fp16 for x (2048 blks), w_qkv (1536), w_out (512);
// mask -> additive bias + per-64-key-tile all-keep flags (16 blks).
// ---------------------------------------------------------------------------
__global__ __launch_bounds__(256) void prep_all(
    const float* __restrict__ x, const float* __restrict__ wq,
    const float* __restrict__ wo, const float* __restrict__ mask,
    _Float16* __restrict__ xh, _Float16* __restrict__ wqh,
    _Float16* __restrict__ woh, float* __restrict__ kbias,
    int* __restrict__ tflags)
{
    int bid = blockIdx.x;
    if (bid >= 4096) {   // mask prep
        int i = (bid - 4096) * 256 + threadIdx.x;
        float mv = mask[i];
        kbias[i] = (mv != 0.f) ? 0.f : -INFINITY;
        unsigned long long bal = __ballot(mv != 0.f);
        if ((threadIdx.x & 63) == 0) tflags[i >> 6] = (bal == ~0ULL) ? 1 : 0;
        return;
    }
    const float* s; _Float16* d; int off;
    if (bid < 2048)      { s = x;  d = xh;  off = bid; }
    else if (bid < 3584) { s = wq; d = wqh; off = bid - 2048; }
    else                 { s = wo; d = woh; off = bid - 3584; }
    int i = (off * 256 + threadIdx.x) * 8;
    float4 a = *(const float4*)(s + i);
    float4 b = *(const float4*)(s + i + 4);
    halfx8 h;
    h[0] = (_Float16)a.x; h[1] = (_Float16)a.y; h[2] = (_Float16)a.z; h[3] = (_Float16)a.w;
    h[4] = (_Float16)b.x; h[5] = (_Float16)b.y; h[6] = (_Float16)b.z; h[7] = (_Float16)b.w;
    *(halfx8*)(d + i) = h;
}

// ---------------------------------------------------------------------------
// GEMM1: qkv = x @ w_qkv^T + b_qkv (fp16 MFMA, 128x128 tile).
// R12: BK=64 via TWIN single-buffers — stage both 32-K sub-tiles (8 copies),
// ONE barrier pair, 32 MFMAs per drain (was 32 x {drain, 16 MFMA}).
// Same transform as R11's gemm_out; here there is 2x the MFMA cover.
// Keeps the proven LDS layout (gload_lds-linear dest, no dbuf hazard).
// Scatter epilogue (R5's LDS transpose measured worse; L2 write-combines).
// ---------------------------------------------------------------------------
__global__ __launch_bounds__(256) void gemm_qkv(
    const _Float16* __restrict__ A, const _Float16* __restrict__ Wt,
    const float* __restrict__ bias,
    _Float16* __restrict__ qh, _Float16* __restrict__ kh, _Float16* __restrict__ vth)
{
    __shared__ _Float16 As[2][128 * 32];
    __shared__ _Float16 Bs[2][128 * 32];
    const int tid = threadIdx.x;
    const int lane = tid & 63, w = tid >> 6;
    const int col = lane & 15, quad = lane >> 4;
    const int wr = w >> 1, wc = w & 1;
    const int m0 = blockIdx.y << 7, n0 = blockIdx.x << 7;

    const int c0 = w * 2, c1 = c0 + 1;
    const int r0 = c0 * 16 + (lane >> 2), r1 = c1 * 16 + (lane >> 2);
    const int ks = (lane & 3) << 3;

    f32x4 acc[4][4] = {};

    for (int k0 = 0; k0 < K_; k0 += 64) {
        ASYNC_COPY16(A  + (size_t)(m0 + r0) * K_ + k0 + ks,      &As[0][c0 * 512]);
        ASYNC_COPY16(A  + (size_t)(m0 + r1) * K_ + k0 + ks,      &As[0][c1 * 512]);
        ASYNC_COPY16(A  + (size_t)(m0 + r0) * K_ + k0 + 32 + ks, &As[1][c0 * 512]);
        ASYNC_COPY16(A  + (size_t)(m0 + r1) * K_ + k0 + 32 + ks, &As[1][c1 * 512]);
        ASYNC_COPY16(Wt + (size_t)(n0 + r0) * K_ + k0 + ks,      &Bs[0][c0 * 512]);
        ASYNC_COPY16(Wt + (size_t)(n0 + r1) * K_ + k0 + ks,      &Bs[0][c1 * 512]);
        ASYNC_COPY16(Wt + (size_t)(n0 + r0) * K_ + k0 + 32 + ks, &Bs[1][c0 * 512]);
        ASYNC_COPY16(Wt + (size_t)(n0 + r1) * K_ + k0 + 32 + ks, &Bs[1][c1 * 512]);
        __syncthreads();
#pragma unroll
        for (int half = 0; half < 2; ++half) {
            halfx8 af[4], bf[4];
#pragma unroll
            for (int i = 0; i < 4; ++i)
                af[i] = *(const halfx8*)&As[half][(wr * 64 + i * 16 + col) * 32 + quad * 8];
#pragma unroll
            for (int j = 0; j < 4; ++j)
                bf[j] = *(const halfx8*)&Bs[half][(wc * 64 + j * 16 + col) * 32 + quad * 8];
#pragma unroll
            for (int i = 0; i < 4; ++i)
#pragma unroll
                for (int j = 0; j < 4; ++j)
                    acc[i][j] = __builtin_amdgcn_mfma_f32_16x16x32_f16(af[i], bf[j], acc[i][j], 0, 0, 0);
        }
        __syncthreads();
    }

#pragma unroll
    for (int i = 0; i < 4; ++i) {
#pragma unroll
        for (int r = 0; r < 4; ++r) {
            int m = m0 + wr * 64 + i * 16 + quad * 4 + r;
            int bb = m >> 11, tt = m & (T_ - 1);
#pragma unroll
            for (int j = 0; j < 4; ++j) {
                int n = n0 + wc * 64 + j * 16 + col;
                float val = acc[i][j][r] + bias[n];
                int which = n >> 10, head = (n >> 6) & 15, dd = n & 63;
                if (which == 0) {
                    qh[((size_t)(bb * H_ + head) * T_ + tt) * HD_ + dd] = (_Float16)(val * QSCALE);
                } else if (which == 1) {
                    int hi = ((dd >> 3) ^ (tt & 7) ^ ((tt >> 3) & 7)) & 7;
                    int dds = (hi << 3) | (dd & 7);
                    kh[((size_t)(bb * H_ + head) * T_ + tt) * HD_ + dds] = (_Float16)val;
                } else {
                    int hi = (((tt >> 3) & 7) ^ (dd & 7) ^ ((dd >> 3) & 7)) & 7;
                    int tts = (tt & ~63) | (hi << 3) | (tt & 7);
                    vth[((size_t)(bb * H_ + head) * HD_ + dd) * T_ + tts] = (_Float16)val;
                }
            }
        }
    }
}

// ---------------------------------------------------------------------------
// GEMM2: out = attn_out @ w_out^T + b_out (fp32 out). 128x64 tile, 512
// blocks. BK=64 twin single-buffers (R11 form; all gemm_out structures
// measured total-neutral — keeping the current one).
// ---------------------------------------------------------------------------
__global__ __launch_bounds__(256) void gemm_out(
    const _Float16* __restrict__ A, const _Float16* __restrict__ Wt,
    const float* __restrict__ bias, float* __restrict__ C)
{
    __shared__ _Float16 As[2][128 * 32];
    __shared__ _Float16 Bs[2][64 * 32];
    const int tid = threadIdx.x;
    const int lane = tid & 63, w = tid >> 6;
    const int col = lane & 15, quad = lane >> 4;
    const int m0 = blockIdx.y << 7, n0 = blockIdx.x << 6;

    const int c0 = w * 2, c1 = c0 + 1;
    const int rA0 = c0 * 16 + (lane >> 2), rA1 = c1 * 16 + (lane >> 2);
    const int rB = w * 16 + (lane >> 2);
    const int ks = (lane & 3) << 3;

    f32x4 acc[2][4] = {};

    for (int k0 = 0; k0 < K_; k0 += 64) {
        ASYNC_COPY16(A  + (size_t)(m0 + rA0) * K_ + k0 + ks,      &As[0][c0 * 512]);
        ASYNC_COPY16(A  + (size_t)(m0 + rA1) * K_ + k0 + ks,      &As[0][c1 * 512]);
        ASYNC_COPY16(A  + (size_t)(m0 + rA0) * K_ + k0 + 32 + ks, &As[1][c0 * 512]);
        ASYNC_COPY16(A  + (size_t)(m0 + rA1) * K_ + k0 + 32 + ks, &As[1][c1 * 512]);
        ASYNC_COPY16(Wt + (size_t)(n0 + rB) * K_ + k0 + ks,       &Bs[0][w * 512]);
        ASYNC_COPY16(Wt + (size_t)(n0 + rB) * K_ + k0 + 32 + ks,  &Bs[1][w * 512]);
        __syncthreads();
#pragma unroll
        for (int half = 0; half < 2; ++half) {
            halfx8 af[2], bf[4];
#pragma unroll
            for (int i = 0; i < 2; ++i)
                af[i] = *(const halfx8*)&As[half][(w * 32 + i * 16 + col) * 32 + quad * 8];
#pragma unroll
            for (int j = 0; j < 4; ++j)
                bf[j] = *(const halfx8*)&Bs[half][(j * 16 + col) * 32 + quad * 8];
#pragma unroll
            for (int i = 0; i < 2; ++i)
#pragma unroll
                for (int j = 0; j < 4; ++j)
                    acc[i][j] = __builtin_amdgcn_mfma_f32_16x16x32_f16(af[i], bf[j], acc[i][j], 0, 0, 0);
        }
        __syncthreads();
    }

#pragma unroll
    for (int i = 0; i < 2; ++i) {
#pragma unroll
        for (int r = 0; r < 4; ++r) {
            int m = m0 + w * 32 + i * 16 + quad * 4 + r;
#pragma unroll
            for (int j = 0; j < 4; ++j) {
                int n = n0 + j * 16 + col;
                C[(size_t)m * D_ + n] = acc[i][j][r] + bias[n];
            }
        }
    }
}

// ---------------------------------------------------------------------------
// Flash attention v13 (R8, measured in best build): HYBRID chunking.
// qt<8 unsplit (final output direct). qt>=8 split in 2 at kt=qt+1 ->
// critical path 32 -> 17 tile-visits. 768 blocks, LPT order.
// ---------------------------------------------------------------------------
__global__ __launch_bounds__(256, 3) void attn_kernel(
    const _Float16* __restrict__ qh, const _Float16* __restrict__ kh,
    const _Float16* __restrict__ vth, const float* __restrict__ kbias,
    const int* __restrict__ tflags,
    float* __restrict__ pm, float* __restrict__ pl,
    _Float16* __restrict__ po, _Float16* __restrict__ oh)
{
    __shared__ _Float16 Ks[2][64 * 64];
    __shared__ _Float16 Vt[2][64 * 64];

    const int item = blockIdx.x >> 5;
    const int qt = QT2_OF[item], c = C2_OF[item];
    const int hb = blockIdx.x & 31;
    const int h = hb & 15, b = hb >> 4;
    const bool split = (qt >= 8);
    const int tid = threadIdx.x;
    const int lane = tid & 63, w = tid >> 6;
    const int l31 = lane & 31, q2 = lane >> 5;

    const int kt0 = (split && c) ? (qt + 1) : 0;
    const int ktend = (split && !c) ? qt : (2 * qt + 1);

    const int bh = b * H_ + h;
    const _Float16* qp = qh + (size_t)bh * T_ * HD_;
    const _Float16* kp = kh + (size_t)bh * T_ * HD_;
    const _Float16* vp = vth + (size_t)bh * HD_ * T_;
    const float* kb = kbias + (size_t)b * T_;
    const int* tf = tflags + b * 32;

    const int qbase = qt * 128 + w * 32;
    const int q_row = qbase + l31;

    // Q B-frags: B[n=q=l31][k = hc*16 + q2*8 + j]
    halfx8 bq[4];
#pragma unroll
    for (int hc = 0; hc < 4; ++hc)
        bq[hc] = *(const halfx8*)(qp + (size_t)q_row * HD_ + hc * 16 + q2 * 8);

    float mrow = -INFINITY;   // deferred running max (scaling base)
    float lrow = 0.f;         // this q2-half's partial sum
    f32x16 oacc[2] = {};
    const fp16x2 one2 = {(__fp16)1.f, (__fp16)1.f};

    // prologue: stage tile kt0 into buffer 0
    {
        const _Float16* ksrc = kp + (size_t)(kt0 * 64 + w * 16) * HD_;
        ASYNC_COPY16(ksrc + lane * 8, &Ks[0][(w * 16) * 64]);
        ASYNC_COPY16(ksrc + 8 * HD_ + lane * 8, &Ks[0][(w * 16 + 8) * 64]);
        const _Float16* vsrc = vp + (size_t)(w * 16 + (lane >> 3)) * T_
                                 + kt0 * 64 + (lane & 7) * 8;
        ASYNC_COPY16(vsrc, &Vt[0][(w * 16) * 64]);
        ASYNC_COPY16(vsrc + 8 * T_, &Vt[0][(w * 16 + 8) * 64]);
    }

    for (int kt = kt0; kt <= ktend; ++kt) {
        const int cur = (kt - kt0) & 1;
        __syncthreads();   // drains async copies for tile kt
        if (kt < ktend) {  // prefetch next tile into other buffer
            const int nb = cur ^ 1;
            const _Float16* ksrc = kp + (size_t)((kt + 1) * 64 + w * 16) * HD_;
            ASYNC_COPY16(ksrc + lane * 8, &Ks[nb][(w * 16) * 64]);
            ASYNC_COPY16(ksrc + 8 * HD_ + lane * 8, &Ks[nb][(w * 16 + 8) * 64]);
            const _Float16* vsrc = vp + (size_t)(w * 16 + (lane >> 3)) * T_
                                     + (kt + 1) * 64 + (lane & 7) * 8;
            ASYNC_COPY16(vsrc, &Vt[nb][(w * 16) * 64]);
            ASYNC_COPY16(vsrc + 8 * T_, &Vt[nb][(w * 16 + 8) * 64]);
        }
        if (kt * 64 > qbase + 31) continue;   // wave-uniform skip

        const int allkeep = tf[kt];
        // number of 32-key halves with any causal-valid key for this wave
        const int kb2max = (qbase + 31 - kt * 64 >= 32) ? 2 : 1;

        // S^T = K·Q^T for BOTH halves first (QK1 latency hides under SM0)
        auto qk_half = [&](int kb2v) -> f32x16 {
            f32x16 a = {};
#pragma unroll
            for (int hc = 0; hc < 4; ++hc) {
                int seg = (hc * 2 + q2) ^ (l31 & 7) ^ ((kb2v * 4 + (l31 >> 3)) & 7);
                halfx8 ka = *(const halfx8*)&Ks[cur][(kb2v * 32 + l31) * 64 + seg * 8];
                a = __builtin_amdgcn_mfma_f32_32x32x16_f16(ka, bq[hc], a, 0, 0, 0);
            }
            return a;
        };
        f32x16 sa0, sa1;
        __builtin_amdgcn_s_setprio(1);
        sa0 = qk_half(0);
        if (kb2max == 2) sa1 = qk_half(1);
        __builtin_amdgcn_s_setprio(0);

        // softmax + PV for one half (a passed by value, kb2v compile-known path)
        auto smpv = [&](const f32x16& a, int kb2v) {
            // local max: max3-fusable triplets (16 -> 6 -> 2 -> 1)
            float t0 = fmaxf(fmaxf(a[0],  a[1]),  a[2]);
            float t1 = fmaxf(fmaxf(a[3],  a[4]),  a[5]);
            float t2 = fmaxf(fmaxf(a[6],  a[7]),  a[8]);
            float t3 = fmaxf(fmaxf(a[9],  a[10]), a[11]);
            float t4 = fmaxf(fmaxf(a[12], a[13]), a[14]);
            float u0 = fmaxf(fmaxf(t0, t1), t2);
            float u1 = fmaxf(fmaxf(t3, t4), a[15]);
            float mx = fmaxf(u0, u1);

            // defer-max: rescale only when some lane exceeds mrow + RTHR
            if (__any(mx > mrow + RTHR)) {
                float mxo = fmaxf(mx, __shfl_xor(mx, 32, 64));
                float mnew = fmaxf(mrow, mxo);
                float alpha = exp2fast(mrow - mnew);   // -inf -> 0
                lrow *= alpha;
#pragma unroll
                for (int db = 0; db < 2; ++db)
#pragma unroll
                    for (int r = 0; r < 16; ++r) oacc[db][r] *= alpha;
                mrow = mnew;
            }

            // P = exp2(s [+bias] - mrow), packed fp16; l via dot2 on packed P
            const bool fastk = allkeep && (kt * 64 + kb2v * 32 + 31 <= qbase);
            halfx4 pf[4];
            float s0 = 0.f, s1 = 0.f;
            if (fastk) {
#pragma unroll
                for (int cc = 0; cc < 4; ++cc) {
                    float e0 = exp2fast(a[cc * 4 + 0] - mrow);
                    float e1 = exp2fast(a[cc * 4 + 1] - mrow);
                    float e2 = exp2fast(a[cc * 4 + 2] - mrow);
                    float e3 = exp2fast(a[cc * 4 + 3] - mrow);
                    fp16x2 lo = __builtin_amdgcn_cvt_pkrtz(e0, e1);
                    fp16x2 hi = __builtin_amdgcn_cvt_pkrtz(e2, e3);
                    halfx2* pfv = (halfx2*)&pf[cc];
                    pfv[0] = __builtin_bit_cast(halfx2, lo);
                    pfv[1] = __builtin_bit_cast(halfx2, hi);
#if __has_builtin(__builtin_amdgcn_fdot2)
                    s0 = __builtin_amdgcn_fdot2(lo, one2, s0, false);
                    s1 = __builtin_amdgcn_fdot2(hi, one2, s1, false);
#else
                    s0 += e0 + e1; s1 += e2 + e3;
#endif
                }
            } else {
#pragma unroll
                for (int cc = 0; cc < 4; ++cc) {
                    float e[4];
#pragma unroll
                    for (int j = 0; j < 4; ++j) {
                        int key = kt * 64 + kb2v * 32 + 8 * cc + 4 * q2 + j;
                        float add = allkeep ? 0.f : kb[key];
                        e[j] = (key <= q_row) ? exp2fast(a[cc * 4 + j] + add - mrow) : 0.f;
                    }
                    fp16x2 lo = __builtin_amdgcn_cvt_pkrtz(e[0], e[1]);
                    fp16x2 hi = __builtin_amdgcn_cvt_pkrtz(e[2], e[3]);
                    halfx2* pfv = (halfx2*)&pf[cc];
                    pfv[0] = __builtin_bit_cast(halfx2, lo);
                    pfv[1] = __builtin_bit_cast(halfx2, hi);
#if __has_builtin(__builtin_amdgcn_fdot2)
                    s0 = __builtin_amdgcn_fdot2(lo, one2, s0, false);
                    s1 = __builtin_amdgcn_fdot2(hi, one2, s1, false);
#else
                    s0 += e[0] + e[1]; s1 += e[2] + e[3];
#endif
                }
            }
            lrow += s0 + s1;

            // O^T += V^T·P^T for this half
            __builtin_amdgcn_s_setprio(1);
#pragma unroll
            for (int db = 0; db < 2; ++db)
#pragma unroll
                for (int cc = 0; cc < 4; ++cc) {
                    int ck = kb2v * 4 + cc;
                    int seg = ck ^ (l31 & 7) ^ ((db * 4 + (l31 >> 3)) & 7);
                    halfx4 va = *(const halfx4*)&Vt[cur][(db * 32 + l31) * 64 + seg * 8 + q2 * 4];
                    oacc[db] = __builtin_amdgcn_mfma_f32_32x32x8f16(va, pf[cc], oacc[db], 0, 0, 0);
                }
            __builtin_amdgcn_s_setprio(0);
        };

        smpv(sa0, 0);
        if (kb2max == 2) smpv(sa1, 1);
    }

    // combine the two q2-halves' l partials
    lrow += __shfl_xor(lrow, 32, 64);

    const int qloc = w * 32 + l31;
    _Float16* ohrow = oh + ((size_t)(b * T_ + qt * 128 + qloc)) * D_ + h * 64;

    if (!split) {
        // final output: normalize in-register, write oh
        const float linv = 1.f / lrow;
#pragma unroll
        for (int db = 0; db < 2; ++db)
#pragma unroll
            for (int gg = 0; gg < 4; ++gg) {
                halfx4 ov;
#pragma unroll
                for (int j = 0; j < 4; ++j)
                    ov[j] = (_Float16)(oacc[db][gg * 4 + j] * linv);
                *(halfx4*)(ohrow + db * 32 + 8 * gg + 4 * q2) = ov;
            }
    } else {
        // partial: m,l to pm/pl; raw O^T to oh (c==0) or po (c==1)
        const int slot = (bh * 8 + (qt - 8)) * 2 + c;
        if (q2 == 0) {
            pm[(size_t)slot * 128 + qloc] = mrow;
            pl[(size_t)slot * 128 + qloc] = lrow;
        }
        _Float16* pob = (c == 0) ? ohrow
                      : po + ((size_t)(bh * 8 + (qt - 8)) * 128 + qloc) * 64;
#pragma unroll
        for (int db = 0; db < 2; ++db)
#pragma unroll
            for (int gg = 0; gg < 4; ++gg) {
                halfx4 ov;
#pragma unroll
                for (int j = 0; j < 4; ++j)
                    ov[j] = (_Float16)(oacc[db][gg * 4 + j]);
                *(halfx4*)(pob + db * 32 + 8 * gg + 4 * q2) = ov;
            }
    }
}

// ---------------------------------------------------------------------------
// Combine (split rows only, qt>=8): merge exactly 2 chunks. Block per
// (qt-8, h, b); thread = (row 0..127, d-half 0..1). c0 partial in oh, c1 in po.
// ---------------------------------------------------------------------------
__global__ __launch_bounds__(256) void attn_combine(
    const float* __restrict__ pm, const float* __restrict__ pl,
    const _Float16* __restrict__ po, _Float16* __restrict__ oh)
{
    const int qi = blockIdx.x;            // qt = qi + 8
    const int h = blockIdx.y, b = blockIdx.z;
    const int bh = b * H_ + h;
    const int tid = threadIdx.x;
    const int r = tid >> 1, dh = tid & 1;

    const int s0 = (bh * 8 + qi) * 2;
    float m0 = pm[(size_t)s0 * 128 + r],       m1 = pm[(size_t)(s0 + 1) * 128 + r];
    float l0 = pl[(size_t)s0 * 128 + r],       l1 = pl[(size_t)(s0 + 1) * 128 + r];
    float ms = fmaxf(m0, m1);
    float w0 = exp2f(m0 - ms), w1 = exp2f(m1 - ms);
    float linv = 1.f / (w0 * l0 + w1 * l1);
    w0 *= linv; w1 *= linv;

    _Float16* ohrow = oh + ((size_t)(b * T_ + (qi + 8) * 128 + r)) * D_ + h * 64 + dh * 32;
    const _Float16* src = po + ((size_t)(bh * 8 + qi) * 128 + r) * 64 + dh * 32;

#pragma unroll
    for (int g = 0; g < 4; ++g) {
        halfx8 o0 = *(const halfx8*)(ohrow + g * 8);
        halfx8 o1 = *(const halfx8*)(src + g * 8);
        halfx8 ov;
#pragma unroll
        for (int j = 0; j < 8; ++j)
            ov[j] = (_Float16)(w0 * (float)o0[j] + w1 * (float)o1[j]);
        *(halfx8*)(ohrow + g * 8) = ov;
    }
}

// ---------------------------------------------------------------------------
extern "C" void kernel_launch(void* const* d_in, const int* in_sizes, int n_in,
                              void* d_out, int out_size, void* d_ws, size_t ws_size,
                              hipStream_t stream)
{
    (void)in_sizes; (void)n_in; (void)out_size; (void)ws_size;
    const float* x     = (const float*)d_in[0];
    const float* mask  = (const float*)d_in[1];
    const float* w_qkv = (const float*)d_in[2];
    const float* b_qkv = (const float*)d_in[3];
    const float* w_out = (const float*)d_in[4];
    const float* b_out = (const float*)d_in[5];
    float* out = (float*)d_out;

    const size_t QKV1 = (size_t)B_ * H_ * T_ * HD_;   // 4.19M halfs
    _Float16* xh  = (_Float16*)d_ws;
    _Float16* wqh = xh  + (size_t)M_ * K_;
    _Float16* woh = wqh + (size_t)N3_ * K_;
    _Float16* qh  = woh + (size_t)D_ * K_;
    _Float16* kh  = qh  + QKV1;
    _Float16* vth = kh  + QKV1;
    _Float16* oh  = vth + QKV1;
    _Float16* po  = oh  + QKV1;                       // 32*8*128*64 halfs = 2M
    float* kbias  = (float*)(po + (size_t)32 * 8 * 128 * 64);
    float* pm     = kbias + (size_t)B_ * T_;          // 32*16*128 floats
    float* pl     = pm + (size_t)32 * 16 * 128;
    int* tflags   = (int*)(pl + (size_t)32 * 16 * 128);  // 64 ints

    prep_all<<<4112, 256, 0, stream>>>(x, w_qkv, w_out, mask,
                                       xh, wqh, woh, kbias, tflags);
    gemm_qkv<<<dim3(N3_ / 128, M_ / 128), 256, 0, stream>>>(
        xh, wqh, b_qkv, qh, kh, vth);
    attn_kernel<<<dim3(768, 1, 1), 256, 0, stream>>>(
        qh, kh, vth, kbias, tflags, pm, pl, po, oh);
    attn_combine<<<dim3(8, H_, B_), 256, 0, stream>>>(
        pm, pl, po, oh);
    gemm_out<<<dim3(D_ / 64, M_ / 128), 256, 0, stream>>>(
        oh, woh, b_out, out);
}

// Round 13
// 179.274 us; speedup vs baseline: 1.0756x; 1.0756x over previous
//
#include <hip/hip_runtime.h>
#include <cmath>

#define B_ 2
#define T_ 2048
#define D_ 1024
#define H_ 16
#define HD_ 64
#define M_ (B_ * T_)   // 4096
#define N3_ (3 * D_)   // 3072
#define K_ 1024

typedef _Float16 halfx8 __attribute__((ext_vector_type(8)));
typedef _Float16 halfx4 __attribute__((ext_vector_type(4)));
typedef _Float16 halfx2 __attribute__((ext_vector_type(2)));
typedef __fp16 fp16x2 __attribute__((ext_vector_type(2)));
typedef float f32x4 __attribute__((ext_vector_type(4)));
typedef float f32x16 __attribute__((ext_vector_type(16)));

#define ASYNC_COPY16(gp, lp) \
  __builtin_amdgcn_global_load_lds((__attribute__((address_space(1))) void*)(gp), \
      (__attribute__((address_space(3))) void*)(lp), 16, 0, 0)

// q pre-scale: 1/sqrt(64) * log2(e)  (softmax in exp2 domain)
#define QSCALE 0.1803368801111204f
// defer-max rescale threshold (exp2 domain): P <= 2^4, fp16-safe partials
#define RTHR 4.0f

__device__ __forceinline__ float exp2fast(float x) {
#if __has_builtin(__builtin_amdgcn_exp2f)
    return __builtin_amdgcn_exp2f(x);
#else
    return exp2f(x);
#endif
}

// Hybrid decomposition: qt>=8 split into 2 chunks (chunk0 = kt 0..qt, all
// interior; chunk1 = kt qt+1..2qt+1, has the causal tail). qt<8 unsplit.
// 24 items per (b,h), ordered LPT-descending by visit count.
__device__ const int QT2_OF[24] = {15,15,7, 14,14, 13,13,6, 12,12, 11,11,5, 10,10, 9,9,4, 8,8, 3,2,1,0};
__device__ const int C2_OF[24]  = { 0, 1,0,  0, 1,  0, 1,0,  0, 1,  0, 1,0,  0, 1, 0,1,0,  0,1, 0,0,0,0};

// ---------------------------------------------------------------------------
// fused prep: fp32->fp16 for x (2048 blks), w_qkv (1536), w_out (512);
// mask -> additive bias + per-64-key-tile all-keep flags (16 blks).
// ---------------------------------------------------------------------------
__global__ __launch_bounds__(256) void prep_all(
    const float* __restrict__ x, const float* __restrict__ wq,
    const float* __restrict__ wo, const float* __restrict__ mask,
    _Float16* __restrict__ xh, _Float16* __restrict__ wqh,
    _Float16* __restrict__ woh, float* __restrict__ kbias,
    int* __restrict__ tflags)
{
    int bid = blockIdx.x;
    if (bid >= 4096) {   // mask prep
        int i = (bid - 4096) * 256 + threadIdx.x;
        float mv = mask[i];
        kbias[i] = (mv != 0.f) ? 0.f : -INFINITY;
        unsigned long long bal = __ballot(mv != 0.f);
        if ((threadIdx.x & 63) == 0) tflags[i >> 6] = (bal == ~0ULL) ? 1 : 0;
        return;
    }
    const float* s; _Float16* d; int off;
    if (bid < 2048)      { s = x;  d = xh;  off = bid; }
    else if (bid < 3584) { s = wq; d = wqh; off = bid - 2048; }
    else                 { s = wo; d = woh; off = bid - 3584; }
    int i = (off * 256 + threadIdx.x) * 8;
    float4 a = *(const float4*)(s + i);
    float4 b = *(const float4*)(s + i + 4);
    halfx8 h;
    h[0] = (_Float16)a.x; h[1] = (_Float16)a.y; h[2] = (_Float16)a.z; h[3] = (_Float16)a.w;
    h[4] = (_Float16)b.x; h[5] = (_Float16)b.y; h[6] = (_Float16)b.z; h[7] = (_Float16)b.w;
    *(halfx8*)(d + i) = h;
}

// ---------------------------------------------------------------------------
// GEMM1: qkv = x @ w_qkv^T + b_qkv (fp16 MFMA, 128x128 tile, BK=32),
// SINGLE-buffered — best-in-TOTAL form, measured twice (R8/R11 = 181.66us).
// dbuf (R9/R10) and BK=64 (R12) both regress the graph total despite local
// per-dispatch wins. Scatter epilogue (R5's LDS transpose measured worse).
// ---------------------------------------------------------------------------
__global__ __launch_bounds__(256) void gemm_qkv(
    const _Float16* __restrict__ A, const _Float16* __restrict__ Wt,
    const float* __restrict__ bias,
    _Float16* __restrict__ qh, _Float16* __restrict__ kh, _Float16* __restrict__ vth)
{
    __shared__ _Float16 As[128 * 32];
    __shared__ _Float16 Bs[128 * 32];
    const int tid = threadIdx.x;
    const int lane = tid & 63, w = tid >> 6;
    const int col = lane & 15, quad = lane >> 4;
    const int wr = w >> 1, wc = w & 1;
    const int m0 = blockIdx.y << 7, n0 = blockIdx.x << 7;

    const int c0 = w * 2, c1 = c0 + 1;
    const int r0 = c0 * 16 + (lane >> 2), r1 = c1 * 16 + (lane >> 2);
    const int ks = (lane & 3) << 3;

    f32x4 acc[4][4] = {};

    for (int k0 = 0; k0 < K_; k0 += 32) {
        ASYNC_COPY16(A  + (size_t)(m0 + r0) * K_ + k0 + ks, &As[c0 * 512]);
        ASYNC_COPY16(A  + (size_t)(m0 + r1) * K_ + k0 + ks, &As[c1 * 512]);
        ASYNC_COPY16(Wt + (size_t)(n0 + r0) * K_ + k0 + ks, &Bs[c0 * 512]);
        ASYNC_COPY16(Wt + (size_t)(n0 + r1) * K_ + k0 + ks, &Bs[c1 * 512]);
        __syncthreads();
        halfx8 af[4], bf[4];
#pragma unroll
        for (int i = 0; i < 4; ++i)
            af[i] = *(const halfx8*)&As[(wr * 64 + i * 16 + col) * 32 + quad * 8];
#pragma unroll
        for (int j = 0; j < 4; ++j)
            bf[j] = *(const halfx8*)&Bs[(wc * 64 + j * 16 + col) * 32 + quad * 8];
#pragma unroll
        for (int i = 0; i < 4; ++i)
#pragma unroll
            for (int j = 0; j < 4; ++j)
                acc[i][j] = __builtin_amdgcn_mfma_f32_16x16x32_f16(af[i], bf[j], acc[i][j], 0, 0, 0);
        __syncthreads();
    }

#pragma unroll
    for (int i = 0; i < 4; ++i) {
#pragma unroll
        for (int r = 0; r < 4; ++r) {
            int m = m0 + wr * 64 + i * 16 + quad * 4 + r;
            int bb = m >> 11, tt = m & (T_ - 1);
#pragma unroll
            for (int j = 0; j < 4; ++j) {
                int n = n0 + wc * 64 + j * 16 + col;
                float val = acc[i][j][r] + bias[n];
                int which = n >> 10, head = (n >> 6) & 15, dd = n & 63;
                if (which == 0) {
                    qh[((size_t)(bb * H_ + head) * T_ + tt) * HD_ + dd] = (_Float16)(val * QSCALE);
                } else if (which == 1) {
                    int hi = ((dd >> 3) ^ (tt & 7) ^ ((tt >> 3) & 7)) & 7;
                    int dds = (hi << 3) | (dd & 7);
                    kh[((size_t)(bb * H_ + head) * T_ + tt) * HD_ + dds] = (_Float16)val;
                } else {
                    int hi = (((tt >> 3) & 7) ^ (dd & 7) ^ ((dd >> 3) & 7)) & 7;
                    int tts = (tt & ~63) | (hi << 3) | (tt & 7);
                    vth[((size_t)(bb * H_ + head) * HD_ + dd) * T_ + tts] = (_Float16)val;
                }
            }
        }
    }
}

// ---------------------------------------------------------------------------
// GEMM2: out = attn_out @ w_out^T + b_out (fp32 out). 128x64 tile, 512
// blocks. BK=64 twin single-buffers (R11 form; all gemm_out structures
// measured total-neutral — keeping the champion build's variant).
// ---------------------------------------------------------------------------
__global__ __launch_bounds__(256) void gemm_out(
    const _Float16* __restrict__ A, const _Float16* __restrict__ Wt,
    const float* __restrict__ bias, float* __restrict__ C)
{
    __shared__ _Float16 As[2][128 * 32];
    __shared__ _Float16 Bs[2][64 * 32];
    const int tid = threadIdx.x;
    const int lane = tid & 63, w = tid >> 6;
    const int col = lane & 15, quad = lane >> 4;
    const int m0 = blockIdx.y << 7, n0 = blockIdx.x << 6;

    const int c0 = w * 2, c1 = c0 + 1;
    const int rA0 = c0 * 16 + (lane >> 2), rA1 = c1 * 16 + (lane >> 2);
    const int rB = w * 16 + (lane >> 2);
    const int ks = (lane & 3) << 3;

    f32x4 acc[2][4] = {};

    for (int k0 = 0; k0 < K_; k0 += 64) {
        ASYNC_COPY16(A  + (size_t)(m0 + rA0) * K_ + k0 + ks,      &As[0][c0 * 512]);
        ASYNC_COPY16(A  + (size_t)(m0 + rA1) * K_ + k0 + ks,      &As[0][c1 * 512]);
        ASYNC_COPY16(A  + (size_t)(m0 + rA0) * K_ + k0 + 32 + ks, &As[1][c0 * 512]);
        ASYNC_COPY16(A  + (size_t)(m0 + rA1) * K_ + k0 + 32 + ks, &As[1][c1 * 512]);
        ASYNC_COPY16(Wt + (size_t)(n0 + rB) * K_ + k0 + ks,       &Bs[0][w * 512]);
        ASYNC_COPY16(Wt + (size_t)(n0 + rB) * K_ + k0 + 32 + ks,  &Bs[1][w * 512]);
        __syncthreads();
#pragma unroll
        for (int half = 0; half < 2; ++half) {
            halfx8 af[2], bf[4];
#pragma unroll
            for (int i = 0; i < 2; ++i)
                af[i] = *(const halfx8*)&As[half][(w * 32 + i * 16 + col) * 32 + quad * 8];
#pragma unroll
            for (int j = 0; j < 4; ++j)
                bf[j] = *(const halfx8*)&Bs[half][(j * 16 + col) * 32 + quad * 8];
#pragma unroll
            for (int i = 0; i < 2; ++i)
#pragma unroll
                for (int j = 0; j < 4; ++j)
                    acc[i][j] = __builtin_amdgcn_mfma_f32_16x16x32_f16(af[i], bf[j], acc[i][j], 0, 0, 0);
        }
        __syncthreads();
    }

#pragma unroll
    for (int i = 0; i < 2; ++i) {
#pragma unroll
        for (int r = 0; r < 4; ++r) {
            int m = m0 + w * 32 + i * 16 + quad * 4 + r;
#pragma unroll
            for (int j = 0; j < 4; ++j) {
                int n = n0 + j * 16 + col;
                C[(size_t)m * D_ + n] = acc[i][j][r] + bias[n];
            }
        }
    }
}

// ---------------------------------------------------------------------------
// Flash attention v13 (R8, measured in best build): HYBRID chunking.
// qt<8 unsplit (final output direct). qt>=8 split in 2 at kt=qt+1 ->
// critical path 32 -> 17 tile-visits. 768 blocks, LPT order.
// ---------------------------------------------------------------------------
__global__ __launch_bounds__(256, 3) void attn_kernel(
    const _Float16* __restrict__ qh, const _Float16* __restrict__ kh,
    const _Float16* __restrict__ vth, const float* __restrict__ kbias,
    const int* __restrict__ tflags,
    float* __restrict__ pm, float* __restrict__ pl,
    _Float16* __restrict__ po, _Float16* __restrict__ oh)
{
    __shared__ _Float16 Ks[2][64 * 64];
    __shared__ _Float16 Vt[2][64 * 64];

    const int item = blockIdx.x >> 5;
    const int qt = QT2_OF[item], c = C2_OF[item];
    const int hb = blockIdx.x & 31;
    const int h = hb & 15, b = hb >> 4;
    const bool split = (qt >= 8);
    const int tid = threadIdx.x;
    const int lane = tid & 63, w = tid >> 6;
    const int l31 = lane & 31, q2 = lane >> 5;

    const int kt0 = (split && c) ? (qt + 1) : 0;
    const int ktend = (split && !c) ? qt : (2 * qt + 1);

    const int bh = b * H_ + h;
    const _Float16* qp = qh + (size_t)bh * T_ * HD_;
    const _Float16* kp = kh + (size_t)bh * T_ * HD_;
    const _Float16* vp = vth + (size_t)bh * HD_ * T_;
    const float* kb = kbias + (size_t)b * T_;
    const int* tf = tflags + b * 32;

    const int qbase = qt * 128 + w * 32;
    const int q_row = qbase + l31;

    // Q B-frags: B[n=q=l31][k = hc*16 + q2*8 + j]
    halfx8 bq[4];
#pragma unroll
    for (int hc = 0; hc < 4; ++hc)
        bq[hc] = *(const halfx8*)(qp + (size_t)q_row * HD_ + hc * 16 + q2 * 8);

    float mrow = -INFINITY;   // deferred running max (scaling base)
    float lrow = 0.f;         // this q2-half's partial sum
    f32x16 oacc[2] = {};
    const fp16x2 one2 = {(__fp16)1.f, (__fp16)1.f};

    // prologue: stage tile kt0 into buffer 0
    {
        const _Float16* ksrc = kp + (size_t)(kt0 * 64 + w * 16) * HD_;
        ASYNC_COPY16(ksrc + lane * 8, &Ks[0][(w * 16) * 64]);
        ASYNC_COPY16(ksrc + 8 * HD_ + lane * 8, &Ks[0][(w * 16 + 8) * 64]);
        const _Float16* vsrc = vp + (size_t)(w * 16 + (lane >> 3)) * T_
                                 + kt0 * 64 + (lane & 7) * 8;
        ASYNC_COPY16(vsrc, &Vt[0][(w * 16) * 64]);
        ASYNC_COPY16(vsrc + 8 * T_, &Vt[0][(w * 16 + 8) * 64]);
    }

    for (int kt = kt0; kt <= ktend; ++kt) {
        const int cur = (kt - kt0) & 1;
        __syncthreads();   // drains async copies for tile kt
        if (kt < ktend) {  // prefetch next tile into other buffer
            const int nb = cur ^ 1;
            const _Float16* ksrc = kp + (size_t)((kt + 1) * 64 + w * 16) * HD_;
            ASYNC_COPY16(ksrc + lane * 8, &Ks[nb][(w * 16) * 64]);
            ASYNC_COPY16(ksrc + 8 * HD_ + lane * 8, &Ks[nb][(w * 16 + 8) * 64]);
            const _Float16* vsrc = vp + (size_t)(w * 16 + (lane >> 3)) * T_
                                     + (kt + 1) * 64 + (lane & 7) * 8;
            ASYNC_COPY16(vsrc, &Vt[nb][(w * 16) * 64]);
            ASYNC_COPY16(vsrc + 8 * T_, &Vt[nb][(w * 16 + 8) * 64]);
        }
        if (kt * 64 > qbase + 31) continue;   // wave-uniform skip

        const int allkeep = tf[kt];
        // number of 32-key halves with any causal-valid key for this wave
        const int kb2max = (qbase + 31 - kt * 64 >= 32) ? 2 : 1;

        // S^T = K·Q^T for BOTH halves first (QK1 latency hides under SM0)
        auto qk_half = [&](int kb2v) -> f32x16 {
            f32x16 a = {};
#pragma unroll
            for (int hc = 0; hc < 4; ++hc) {
                int seg = (hc * 2 + q2) ^ (l31 & 7) ^ ((kb2v * 4 + (l31 >> 3)) & 7);
                halfx8 ka = *(const halfx8*)&Ks[cur][(kb2v * 32 + l31) * 64 + seg * 8];
                a = __builtin_amdgcn_mfma_f32_32x32x16_f16(ka, bq[hc], a, 0, 0, 0);
            }
            return a;
        };
        f32x16 sa0, sa1;
        __builtin_amdgcn_s_setprio(1);
        sa0 = qk_half(0);
        if (kb2max == 2) sa1 = qk_half(1);
        __builtin_amdgcn_s_setprio(0);

        // softmax + PV for one half (a passed by value, kb2v compile-known path)
        auto smpv = [&](const f32x16& a, int kb2v) {
            // local max: max3-fusable triplets (16 -> 6 -> 2 -> 1)
            float t0 = fmaxf(fmaxf(a[0],  a[1]),  a[2]);
            float t1 = fmaxf(fmaxf(a[3],  a[4]),  a[5]);
            float t2 = fmaxf(fmaxf(a[6],  a[7]),  a[8]);
            float t3 = fmaxf(fmaxf(a[9],  a[10]), a[11]);
            float t4 = fmaxf(fmaxf(a[12], a[13]), a[14]);
            float u0 = fmaxf(fmaxf(t0, t1), t2);
            float u1 = fmaxf(fmaxf(t3, t4), a[15]);
            float mx = fmaxf(u0, u1);

            // defer-max: rescale only when some lane exceeds mrow + RTHR
            if (__any(mx > mrow + RTHR)) {
                float mxo = fmaxf(mx, __shfl_xor(mx, 32, 64));
                float mnew = fmaxf(mrow, mxo);
                float alpha = exp2fast(mrow - mnew);   // -inf -> 0
                lrow *= alpha;
#pragma unroll
                for (int db = 0; db < 2; ++db)
#pragma unroll
                    for (int r = 0; r < 16; ++r) oacc[db][r] *= alpha;
                mrow = mnew;
            }

            // P = exp2(s [+bias] - mrow), packed fp16; l via dot2 on packed P
            const bool fastk = allkeep && (kt * 64 + kb2v * 32 + 31 <= qbase);
            halfx4 pf[4];
            float s0 = 0.f, s1 = 0.f;
            if (fastk) {
#pragma unroll
                for (int cc = 0; cc < 4; ++cc) {
                    float e0 = exp2fast(a[cc * 4 + 0] - mrow);
                    float e1 = exp2fast(a[cc * 4 + 1] - mrow);
                    float e2 = exp2fast(a[cc * 4 + 2] - mrow);
                    float e3 = exp2fast(a[cc * 4 + 3] - mrow);
                    fp16x2 lo = __builtin_amdgcn_cvt_pkrtz(e0, e1);
                    fp16x2 hi = __builtin_amdgcn_cvt_pkrtz(e2, e3);
                    halfx2* pfv = (halfx2*)&pf[cc];
                    pfv[0] = __builtin_bit_cast(halfx2, lo);
                    pfv[1] = __builtin_bit_cast(halfx2, hi);
#if __has_builtin(__builtin_amdgcn_fdot2)
                    s0 = __builtin_amdgcn_fdot2(lo, one2, s0, false);
                    s1 = __builtin_amdgcn_fdot2(hi, one2, s1, false);
#else
                    s0 += e0 + e1; s1 += e2 + e3;
#endif
                }
            } else {
#pragma unroll
                for (int cc = 0; cc < 4; ++cc) {
                    float e[4];
#pragma unroll
                    for (int j = 0; j < 4; ++j) {
                        int key = kt * 64 + kb2v * 32 + 8 * cc + 4 * q2 + j;
                        float add = allkeep ? 0.f : kb[key];
                        e[j] = (key <= q_row) ? exp2fast(a[cc * 4 + j] + add - mrow) : 0.f;
                    }
                    fp16x2 lo = __builtin_amdgcn_cvt_pkrtz(e[0], e[1]);
                    fp16x2 hi = __builtin_amdgcn_cvt_pkrtz(e[2], e[3]);
                    halfx2* pfv = (halfx2*)&pf[cc];
                    pfv[0] = __builtin_bit_cast(halfx2, lo);
                    pfv[1] = __builtin_bit_cast(halfx2, hi);
#if __has_builtin(__builtin_amdgcn_fdot2)
                    s0 = __builtin_amdgcn_fdot2(lo, one2, s0, false);
                    s1 = __builtin_amdgcn_fdot2(hi, one2, s1, false);
#else
                    s0 += e[0] + e[1]; s1 += e[2] + e[3];
#endif
                }
            }
            lrow += s0 + s1;

            // O^T += V^T·P^T for this half
            __builtin_amdgcn_s_setprio(1);
#pragma unroll
            for (int db = 0; db < 2; ++db)
#pragma unroll
                for (int cc = 0; cc < 4; ++cc) {
                    int ck = kb2v * 4 + cc;
                    int seg = ck ^ (l31 & 7) ^ ((db * 4 + (l31 >> 3)) & 7);
                    halfx4 va = *(const halfx4*)&Vt[cur][(db * 32 + l31) * 64 + seg * 8 + q2 * 4];
                    oacc[db] = __builtin_amdgcn_mfma_f32_32x32x8f16(va, pf[cc], oacc[db], 0, 0, 0);
                }
            __builtin_amdgcn_s_setprio(0);
        };

        smpv(sa0, 0);
        if (kb2max == 2) smpv(sa1, 1);
    }

    // combine the two q2-halves' l partials
    lrow += __shfl_xor(lrow, 32, 64);

    const int qloc = w * 32 + l31;
    _Float16* ohrow = oh + ((size_t)(b * T_ + qt * 128 + qloc)) * D_ + h * 64;

    if (!split) {
        // final output: normalize in-register, write oh
        const float linv = 1.f / lrow;
#pragma unroll
        for (int db = 0; db < 2; ++db)
#pragma unroll
            for (int gg = 0; gg < 4; ++gg) {
                halfx4 ov;
#pragma unroll
                for (int j = 0; j < 4; ++j)
                    ov[j] = (_Float16)(oacc[db][gg * 4 + j] * linv);
                *(halfx4*)(ohrow + db * 32 + 8 * gg + 4 * q2) = ov;
            }
    } else {
        // partial: m,l to pm/pl; raw O^T to oh (c==0) or po (c==1)
        const int slot = (bh * 8 + (qt - 8)) * 2 + c;
        if (q2 == 0) {
            pm[(size_t)slot * 128 + qloc] = mrow;
            pl[(size_t)slot * 128 + qloc] = lrow;
        }
        _Float16* pob = (c == 0) ? ohrow
                      : po + ((size_t)(bh * 8 + (qt - 8)) * 128 + qloc) * 64;
#pragma unroll
        for (int db = 0; db < 2; ++db)
#pragma unroll
            for (int gg = 0; gg < 4; ++gg) {
                halfx4 ov;
#pragma unroll
                for (int j = 0; j < 4; ++j)
                    ov[j] = (_Float16)(oacc[db][gg * 4 + j]);
                *(halfx4*)(pob + db * 32 + 8 * gg + 4 * q2) = ov;
            }
    }
}

// ---------------------------------------------------------------------------
// Combine (split rows only, qt>=8): merge exactly 2 chunks. Block per
// (qt-8, h, b); thread = (row 0..127, d-half 0..1). c0 partial in oh, c1 in po.
// ---------------------------------------------------------------------------
__global__ __launch_bounds__(256) void attn_combine(
    const float* __restrict__ pm, const float* __restrict__ pl,
    const _Float16* __restrict__ po, _Float16* __restrict__ oh)
{
    const int qi = blockIdx.x;            // qt = qi + 8
    const int h = blockIdx.y, b = blockIdx.z;
    const int bh = b * H_ + h;
    const int tid = threadIdx.x;
    const int r = tid >> 1, dh = tid & 1;

    const int s0 = (bh * 8 + qi) * 2;
    float m0 = pm[(size_t)s0 * 128 + r],       m1 = pm[(size_t)(s0 + 1) * 128 + r];
    float l0 = pl[(size_t)s0 * 128 + r],       l1 = pl[(size_t)(s0 + 1) * 128 + r];
    float ms = fmaxf(m0, m1);
    float w0 = exp2f(m0 - ms), w1 = exp2f(m1 - ms);
    float linv = 1.f / (w0 * l0 + w1 * l1);
    w0 *= linv; w1 *= linv;

    _Float16* ohrow = oh + ((size_t)(b * T_ + (qi + 8) * 128 + r)) * D_ + h * 64 + dh * 32;
    const _Float16* src = po + ((size_t)(bh * 8 + qi) * 128 + r) * 64 + dh * 32;

#pragma unroll
    for (int g = 0; g < 4; ++g) {
        halfx8 o0 = *(const halfx8*)(ohrow + g * 8);
        halfx8 o1 = *(const halfx8*)(src + g * 8);
        halfx8 ov;
#pragma unroll
        for (int j = 0; j < 8; ++j)
            ov[j] = (_Float16)(w0 * (float)o0[j] + w1 * (float)o1[j]);
        *(halfx8*)(ohrow + g * 8) = ov;
    }
}

// ---------------------------------------------------------------------------
extern "C" void kernel_launch(void* const* d_in, const int* in_sizes, int n_in,
                              void* d_out, int out_size, void* d_ws, size_t ws_size,
                              hipStream_t stream)
{
    (void)in_sizes; (void)n_in; (void)out_size; (void)ws_size;
    const float* x     = (const float*)d_in[0];
    const float* mask  = (const float*)d_in[1];
    const float* w_qkv = (const float*)d_in[2];
    const float* b_qkv = (const float*)d_in[3];
    const float* w_out = (const float*)d_in[4];
    const float* b_out = (const float*)d_in[5];
    float* out = (float*)d_out;

    const size_t QKV1 = (size_t)B_ * H_ * T_ * HD_;   // 4.19M halfs
    _Float16* xh  = (_Float16*)d_ws;
    _Float16* wqh = xh  + (size_t)M_ * K_;
    _Float16* woh = wqh + (size_t)N3_ * K_;
    _Float16* qh  = woh + (size_t)D_ * K_;
    _Float16* kh  = qh  + QKV1;
    _Float16* vth = kh  + QKV1;
    _Float16* oh  = vth + QKV1;
    _Float16* po  = oh  + QKV1;                       // 32*8*128*64 halfs = 2M
    float* kbias  = (float*)(po + (size_t)32 * 8 * 128 * 64);
    float* pm     = kbias + (size_t)B_ * T_;          // 32*16*128 floats
    float* pl     = pm + (size_t)32 * 16 * 128;
    int* tflags   = (int*)(pl + (size_t)32 * 16 * 128);  // 64 ints

    prep_all<<<4112, 256, 0, stream>>>(x, w_qkv, w_out, mask,
                                       xh, wqh, woh, kbias, tflags);
    gemm_qkv<<<dim3(N3_ / 128, M_ / 128), 256, 0, stream>>>(
        xh, wqh, b_qkv, qh, kh, vth);
    attn_kernel<<<dim3(768, 1, 1), 256, 0, stream>>>(
        qh, kh, vth, kbias, tflags, pm, pl, po, oh);
    attn_combine<<<dim3(8, H_, B_), 256, 0, stream>>>(
        pm, pl, po, oh);
    gemm_out<<<dim3(D_ / 64, M_ / 128), 256, 0, stream>>>(
        oh, woh, b_out, out);
}